// Round 3
// baseline (96.227 us; speedup 1.0000x reference)
//
#include <hip/hip_runtime.h>

#define W 512

__device__ __forceinline__ float fexp2(float x) {
#if __has_builtin(__builtin_amdgcn_exp2f)
    return __builtin_amdgcn_exp2f(x);
#else
    return __expf(x * 0.6931471805599453f);
#endif
}

// ---------------- tiny min/max pre-pass: 256 contention-free partials ----------------
__global__ __launch_bounds__(256) void k_minmax(const float* __restrict__ y,
                                                float2* __restrict__ partial) {
    __shared__ float smn[256], smx[256];
    int t = threadIdx.x;
    const float4* y4 = (const float4*)y;
    float4 v = y4[blockIdx.x * 256 + t];
    float mn = fminf(fminf(v.x, v.y), fminf(v.z, v.w));
    float mx = fmaxf(fmaxf(v.x, v.y), fmaxf(v.z, v.w));
    smn[t] = mn; smx[t] = mx;
    __syncthreads();
    for (int off = 128; off > 0; off >>= 1) {
        if (t < off) {
            smn[t] = fminf(smn[t], smn[t + off]);
            smx[t] = fmaxf(smx[t], smx[t + off]);
        }
        __syncthreads();
    }
    if (t == 0) partial[blockIdx.x] = make_float2(smn[0], smx[0]);
}

// ---------------- box kernel: produce (Xb,yb) and (Xd,Dd) for every pixel --------
// 16x16 tile, 9x9 zero-padded box (/81 uniform), identical math to fused phases.
// Block (0,0) additionally reduces the 256 min/max partials -> k2 scalar.
__global__ __launch_bounds__(256) void k_box(const float* __restrict__ X,
                                             const float* __restrict__ y,
                                             const float2* __restrict__ partial,
                                             const float* __restrict__ r,
                                             float2* __restrict__ bXY_g,
                                             float2* __restrict__ dXD_g,
                                             float* __restrict__ k2out) {
    __shared__ __align__(16) float lds[1920];
    float* sX  = lds;          // 24*24
    float* sY  = sX + 576;     // 24*24
    float* csX = sY + 576;     // 16*24
    float* csY = csX + 384;    // 16*24

    int tx = threadIdx.x, ty = threadIdx.y;
    int t = ty * 16 + tx;
    int c0 = blockIdx.x * 16, r0 = blockIdx.y * 16;

    if (blockIdx.x == 0 && blockIdx.y == 0) {
        float2* red = (float2*)lds;             // alias, dead before staging
        red[t] = partial[t];
        __syncthreads();
        for (int off = 128; off > 0; off >>= 1) {
            if (t < off) {
                red[t].x = fminf(red[t].x, red[t + off].x);
                red[t].y = fmaxf(red[t].y, red[t + off].y);
            }
            __syncthreads();
        }
        if (t == 0) {
            float sigma = r[0] * (red[0].y - red[0].x);
            float hh = 0.5f * sigma;
            k2out[0] = -1.4426950408889634f / (hh * hh);
        }
        __syncthreads();
    }

    // stage 24x24 X,y with halo 4 (zero outside image)
    for (int i = t; i < 576; i += 256) {
        int rr = i / 24, cc = i - rr * 24;
        int gr = r0 - 4 + rr, gc = c0 - 4 + cc;
        bool ok = ((unsigned)gr < 512u) & ((unsigned)gc < 512u);
        float xv = 0.f, yv = 0.f;
        if (ok) { xv = X[gr * W + gc]; yv = y[gr * W + gc]; }
        sX[i] = xv; sY[i] = yv;
    }
    __syncthreads();

    // 9-row column sums
    for (int i = t; i < 384; i += 256) {
        int rr = i / 24, cc = i - rr * 24;
        float ax = 0.f, ay = 0.f;
#pragma unroll
        for (int k = 0; k < 9; ++k) { ax += sX[(rr + k) * 24 + cc]; ay += sY[(rr + k) * 24 + cc]; }
        csX[i] = ax; csY[i] = ay;
    }
    __syncthreads();

    // 9-col sums -> per-pixel base + detail, write to global
    const float inv81 = 1.0f / 81.0f;
    float ax = 0.f, ay = 0.f;
#pragma unroll
    for (int k = 0; k < 9; ++k) { ax += csX[ty * 24 + tx + k]; ay += csY[ty * 24 + tx + k]; }
    float Xb = ax * inv81, yb = ay * inv81;
    float xc = sX[(ty + 4) * 24 + tx + 4];
    float yc = sY[(ty + 4) * 24 + tx + 4];
    float xd = xc - Xb;
    int p = (r0 + ty) * W + (c0 + tx);
    bXY_g[p] = make_float2(Xb, yb);
    dXD_g[p] = make_float2(xd, (yc - yb) - xd);
}

// ---------------- lean bilateral kernel: stage precomputed tiles, 1 barrier ------
__global__ __launch_bounds__(256, 4) void k_bil(const float2* __restrict__ bXY_g,
                                                const float2* __restrict__ dXD_g,
                                                const float* __restrict__ k2buf,
                                                float* __restrict__ out) {
    __shared__ float sbx[19];
    __shared__ float sdy[5];
    __shared__ __align__(16) float2 bXYs[34 * 34];   // rows r0-9..r0+24, cols c0-9..c0+24
    __shared__ __align__(16) float2 dXDs[20 * 24];   // rows r0-2..r0+17, cols c0-4..c0+19

    int tx = threadIdx.x, ty = threadIdx.y;
    int t = ty * 16 + tx;
    int c0 = blockIdx.x * 16, r0 = blockIdx.y * 16;

    if (t < 19)      { int d = t - 9;  sbx[t]      = __expf(-(float)(d * d) / 8145.0625f); }
    else if (t < 24) { int d = t - 21; sdy[t - 19] = __expf(-(float)(d * d) / 126.5625f); }

    float k2 = k2buf[0];

    for (int i = t; i < 34 * 34; i += 256) {
        int rr = i / 34, cc2 = i - rr * 34;
        int gr = r0 - 9 + rr, gc = c0 - 9 + cc2;
        float2 v = make_float2(0.f, 0.f);
        if (((unsigned)gr < 512u) & ((unsigned)gc < 512u)) v = bXY_g[gr * W + gc];
        bXYs[i] = v;
    }
    for (int i = t; i < 20 * 24; i += 256) {
        int rr = i / 24, cc2 = i - rr * 24;
        int gr = r0 - 2 + rr, gc = c0 - 4 + cc2;
        float2 v = make_float2(0.f, 0.f);
        if (((unsigned)gr < 512u) & ((unsigned)gc < 512u)) v = dXD_g[gr * W + gc];
        dXDs[i] = v;
    }
    __syncthreads();

    int c = c0 + tx;
    int h = r0 + ty;

    // chunk mapping: output col -> owning chunk after overlap-trim
    int chunk = (c == 0) ? 0 : (c - 1) / 62;
    if (chunk > 8) chunk = 8;
    int s = 62 * chunk;
    int e = (chunk == 8) ? 512 : (s + 64);

    const float ksb = -1.4426950408889634f / 8145.0625f;
    const float ksd = -1.4426950408889634f / 126.5625f;
    float cc[19];
#pragma unroll
    for (int j = 0; j < 19; ++j) {
        int nc = c - 9 + j, d = j - 9;
        cc[j] = ((nc >= s) & (nc < e)) ? ksb * (float)(d * d) : -1e30f;
    }
    float ccd[9];
#pragma unroll
    for (int j = 0; j < 9; ++j) {
        int nc = c - 4 + j, d = j - 4;
        ccd[j] = ((nc >= s) & (nc < e)) ? ksd * (float)(d * d) : -1e30f;
    }

    float Xc = bXYs[(ty + 9) * 34 + tx + 9].x;
    float Xd = dXDs[(ty + 2) * 24 + tx + 4].x;

    // ---- base pass: 19x19 bilateral guided-filter stats ----
    float sw = 0.f, swx = 0.f, swy = 0.f, swxx = 0.f, swxy = 0.f;
#pragma unroll 1
    for (int k = 0; k < 19; ++k) {
        int nh = h - 9 + k;
        if ((unsigned)nh >= 512u) continue;
        const float2* xr = (const float2*)bXYs + (ty + k) * 34 + tx;
        float rs = 0.f, rsx = 0.f, rsy = 0.f, rsxx = 0.f, rsxy = 0.f;
#pragma unroll
        for (int j = 0; j < 19; ++j) {
            float2 v = xr[j];
            float u = v.x - Xc;
            float a = fmaf(u * k2, u, cc[j]);
            float w = fexp2(a);
            rs += w;
            rsx = fmaf(w, v.x, rsx);
            rsy = fmaf(w, v.y, rsy);
            float tt = w * v.x;
            rsxx = fmaf(tt, v.x, rsxx);
            rsxy = fmaf(tt, v.y, rsxy);
        }
        float ey = sbx[k];
        sw   = fmaf(ey, rs,   sw);
        swx  = fmaf(ey, rsx,  swx);
        swy  = fmaf(ey, rsy,  swy);
        swxx = fmaf(ey, rsxx, swxx);
        swxy = fmaf(ey, rsxy, swxy);
    }

    // ---- detail pass: 5(h)x9(w) bilateral on residuals ----
    float swd = 0.f, sv = 0.f;
#pragma unroll 1
    for (int k = 0; k < 5; ++k) {
        int nh = h - 2 + k;
        if ((unsigned)nh >= 512u) continue;
        const float2* dr2 = (const float2*)dXDs + (ty + k) * 24 + tx;
        float rs = 0.f, rv = 0.f;
#pragma unroll
        for (int j = 0; j < 9; ++j) {
            float2 v = dr2[j];
            float u = v.x - Xd;
            float a = fmaf(u * k2, u, ccd[j]);
            float w = fexp2(a);
            rs += w;
            rv = fmaf(w, v.y, rv);
        }
        swd = fmaf(sdy[k], rs, swd);
        sv  = fmaf(sdy[k], rv, sv);
    }

    float inv  = 1.0f / sw;
    float mx   = swx * inv, my = swy * inv;
    float varx = fmaf(-mx, mx, swxx * inv);
    float cov  = fmaf(-mx, my, swxy * inv);
    float A    = cov / (varx + 1e-6f);
    float b    = my - A * mx;
    float bd   = sv / swd;
    out[h * W + c] = fmaf(A, Xc, b) + Xd + bd;
}

// ---------------- fallback: R1 fused kernel (used only if workspace too small) ---
__global__ __launch_bounds__(256, 4) void k_fused(const float* __restrict__ X,
                                                  const float* __restrict__ y,
                                                  const float2* __restrict__ partial,
                                                  const float* __restrict__ r,
                                                  float* __restrict__ out) {
    __shared__ float sbx[19];
    __shared__ float sdy[5];
    __shared__ __align__(16) char ldsbuf[38624];
    float*  sX  = (float*)ldsbuf;
    float*  sY  = sX + 42 * 42;
    float*  csX = sY + 42 * 42;
    float*  csY = csX + 34 * 42;
    float2* bXY = (float2*)(csY + 34 * 42);
    float2* dXD = bXY + 34 * 34;
    float2* red = (float2*)sX;

    int tx = threadIdx.x, ty = threadIdx.y;
    int t = ty * 16 + tx;
    int c0 = blockIdx.x * 16, r0 = blockIdx.y * 16;

    if (t < 19)      { int d = t - 9;  sbx[t]      = __expf(-(float)(d * d) / 8145.0625f); }
    else if (t < 24) { int d = t - 21; sdy[t - 19] = __expf(-(float)(d * d) / 126.5625f); }

    red[t] = partial[t];
    __syncthreads();
    for (int off = 128; off > 0; off >>= 1) {
        if (t < off) {
            red[t].x = fminf(red[t].x, red[t + off].x);
            red[t].y = fmaxf(red[t].y, red[t + off].y);
        }
        __syncthreads();
    }
    float2 mm0 = red[0];
    __syncthreads();
    float sigma = r[0] * (mm0.y - mm0.x);
    float hh = 0.5f * sigma;
    float k2 = -1.4426950408889634f / (hh * hh);

    for (int i = t; i < 42 * 42; i += 256) {
        int rr = i / 42, cc2 = i - rr * 42;
        int gr = r0 - 13 + rr, gc = c0 - 13 + cc2;
        bool ok = ((unsigned)gr < 512u) & ((unsigned)gc < 512u);
        float xv = 0.f, yv = 0.f;
        if (ok) { xv = X[gr * W + gc]; yv = y[gr * W + gc]; }
        sX[i] = xv; sY[i] = yv;
    }
    __syncthreads();

    for (int i = t; i < 34 * 42; i += 256) {
        int rr = i / 42, cc2 = i - rr * 42;
        float ax = 0.f, ay = 0.f;
#pragma unroll
        for (int k = 0; k < 9; ++k) { ax += sX[(rr + k) * 42 + cc2]; ay += sY[(rr + k) * 42 + cc2]; }
        csX[i] = ax; csY[i] = ay;
    }
    __syncthreads();

    const float inv81 = 1.0f / 81.0f;
    for (int i = t; i < 34 * 34; i += 256) {
        int rr = i / 34, cc2 = i - rr * 34;
        float ax = 0.f, ay = 0.f;
#pragma unroll
        for (int k = 0; k < 9; ++k) { ax += csX[rr * 42 + cc2 + k]; ay += csY[rr * 42 + cc2 + k]; }
        bXY[i] = make_float2(ax * inv81, ay * inv81);
    }
    __syncthreads();

    for (int i = t; i < 20 * 24; i += 256) {
        int rr = i / 24, cc2 = i - rr * 24;
        float2 b2 = bXY[(rr + 7) * 34 + (cc2 + 5)];
        float xc = sX[(rr + 11) * 42 + (cc2 + 9)];
        float yc = sY[(rr + 11) * 42 + (cc2 + 9)];
        float xd = xc - b2.x;
        dXD[i] = make_float2(xd, (yc - b2.y) - xd);
    }
    __syncthreads();

    int c = c0 + tx;
    int h = r0 + ty;
    int chunk = (c == 0) ? 0 : (c - 1) / 62;
    if (chunk > 8) chunk = 8;
    int s = 62 * chunk;
    int e = (chunk == 8) ? 512 : (s + 64);

    const float ksb = -1.4426950408889634f / 8145.0625f;
    const float ksd = -1.4426950408889634f / 126.5625f;
    float cc[19];
#pragma unroll
    for (int j = 0; j < 19; ++j) {
        int nc = c - 9 + j, d = j - 9;
        cc[j] = ((nc >= s) & (nc < e)) ? ksb * (float)(d * d) : -1e30f;
    }
    float ccd[9];
#pragma unroll
    for (int j = 0; j < 9; ++j) {
        int nc = c - 4 + j, d = j - 4;
        ccd[j] = ((nc >= s) & (nc < e)) ? ksd * (float)(d * d) : -1e30f;
    }

    float Xc = bXY[(ty + 9) * 34 + tx + 9].x;
    float Xd = dXD[(ty + 2) * 24 + tx + 4].x;

    float sw = 0.f, swx = 0.f, swy = 0.f, swxx = 0.f, swxy = 0.f;
#pragma unroll 1
    for (int k = 0; k < 19; ++k) {
        int nh = h - 9 + k;
        if ((unsigned)nh >= 512u) continue;
        const float2* xr = bXY + (ty + k) * 34 + tx;
        float rs = 0.f, rsx = 0.f, rsy = 0.f, rsxx = 0.f, rsxy = 0.f;
#pragma unroll
        for (int j = 0; j < 19; ++j) {
            float2 v = xr[j];
            float u = v.x - Xc;
            float a = fmaf(u * k2, u, cc[j]);
            float w = fexp2(a);
            rs += w;
            rsx = fmaf(w, v.x, rsx);
            rsy = fmaf(w, v.y, rsy);
            float tt = w * v.x;
            rsxx = fmaf(tt, v.x, rsxx);
            rsxy = fmaf(tt, v.y, rsxy);
        }
        float ey = sbx[k];
        sw   = fmaf(ey, rs,   sw);
        swx  = fmaf(ey, rsx,  swx);
        swy  = fmaf(ey, rsy,  swy);
        swxx = fmaf(ey, rsxx, swxx);
        swxy = fmaf(ey, rsxy, swxy);
    }

    float swd = 0.f, sv = 0.f;
#pragma unroll 1
    for (int k = 0; k < 5; ++k) {
        int nh = h - 2 + k;
        if ((unsigned)nh >= 512u) continue;
        const float2* dr2 = dXD + (ty + k) * 24 + tx;
        float rs = 0.f, rv = 0.f;
#pragma unroll
        for (int j = 0; j < 9; ++j) {
            float2 v = dr2[j];
            float u = v.x - Xd;
            float a = fmaf(u * k2, u, ccd[j]);
            float w = fexp2(a);
            rs += w;
            rv = fmaf(w, v.y, rv);
        }
        swd = fmaf(sdy[k], rs, swd);
        sv  = fmaf(sdy[k], rv, sv);
    }

    float inv  = 1.0f / sw;
    float mx   = swx * inv, my = swy * inv;
    float varx = fmaf(-mx, mx, swxx * inv);
    float cov  = fmaf(-mx, my, swxy * inv);
    float A    = cov / (varx + 1e-6f);
    float b    = my - A * mx;
    float bd   = sv / swd;
    out[h * W + c] = fmaf(A, Xc, b) + Xd + bd;
}

extern "C" void kernel_launch(void* const* d_in, const int* in_sizes, int n_in,
                              void* d_out, int out_size, void* d_ws, size_t ws_size,
                              hipStream_t stream) {
    const float* X = (const float*)d_in[0];
    const float* y = (const float*)d_in[1];
    const float* r = (const float*)d_in[2];
    float* out = (float*)d_out;

    float2* partial = (float2*)d_ws;                               // 2048 B
    float*  k2buf   = (float*)((char*)d_ws + 2048);                // 4 B (padded)
    float2* bXY_g   = (float2*)((char*)d_ws + 4096);               // 2 MB
    float2* dXD_g   = (float2*)((char*)d_ws + 4096 + 512 * 512 * 8); // 2 MB
    size_t need = 4096 + (size_t)2 * 512 * 512 * 8;

    k_minmax<<<256, 256, 0, stream>>>(y, partial);
    if (ws_size >= need) {
        k_box<<<dim3(32, 32), dim3(16, 16), 0, stream>>>(X, y, partial, r, bXY_g, dXD_g, k2buf);
        k_bil<<<dim3(32, 32), dim3(16, 16), 0, stream>>>(bXY_g, dXD_g, k2buf, out);
    } else {
        k_fused<<<dim3(32, 32), dim3(16, 16), 0, stream>>>(X, y, partial, r, out);
    }
}

// Round 4
// 95.411 us; speedup vs baseline: 1.0086x; 1.0086x over previous
//
#include <hip/hip_runtime.h>

#define W 512

typedef float v2f __attribute__((ext_vector_type(2)));

__device__ __forceinline__ float fexp2(float x) {
#if __has_builtin(__builtin_amdgcn_exp2f)
    return __builtin_amdgcn_exp2f(x);
#else
    return __expf(x * 0.6931471805599453f);
#endif
}
__device__ __forceinline__ v2f vfma(v2f a, v2f b, v2f c) {
    return __builtin_elementwise_fma(a, b, c);
}
__device__ __forceinline__ v2f bc2(float x) { v2f r; r.x = x; r.y = x; return r; }

// ---------------- tiny min/max pre-pass: 256 contention-free partials ----------------
__global__ __launch_bounds__(256) void k_minmax(const float* __restrict__ y,
                                                float2* __restrict__ partial) {
    __shared__ float smn[256], smx[256];
    int t = threadIdx.x;
    const float4* y4 = (const float4*)y;
    float4 v = y4[blockIdx.x * 256 + t];
    float mn = fminf(fminf(v.x, v.y), fminf(v.z, v.w));
    float mx = fmaxf(fmaxf(v.x, v.y), fmaxf(v.z, v.w));
    smn[t] = mn; smx[t] = mx;
    __syncthreads();
    for (int off = 128; off > 0; off >>= 1) {
        if (t < off) {
            smn[t] = fminf(smn[t], smn[t + off]);
            smx[t] = fmaxf(smx[t], smx[t + off]);
        }
        __syncthreads();
    }
    if (t == 0) partial[blockIdx.x] = make_float2(smn[0], smx[0]);
}

// ---------------- fused kernel: box + bilateral, SoA LDS, packed-f32 inner loop ----
// 16x16 tile, 1 px/thread, grid 32x32 = 1024 blocks -> 4 blocks/CU (arena 35.3 KB).
// j-dimension processed in v2f pairs -> v_pk_* math; pair-pad columns zeroed, pad
// exponents -1e30 (exp2 -> exact 0, 0*finite = 0).
__global__ __launch_bounds__(256, 4) void k_fused(const float* __restrict__ X,
                                                  const float* __restrict__ y,
                                                  const float2* __restrict__ partial,
                                                  const float* __restrict__ r,
                                                  float* __restrict__ out) {
    __shared__ float sbx[19];   // row spatial weights, 19x19 filter
    __shared__ float sdy[5];    // row spatial weights, 5x9 filter
    __shared__ float sk2;
    __shared__ __align__(16) float arena[8832];   // 35328 B
    float* sX  = arena;          // 42*42  rows r0-13..r0+28, cols c0-13..c0+28
    float* sY  = sX + 1764;      // 42*42
    float* csX = sY + 1764;      // 34*42  @3528
    float* csY = csX + 1428;     // 34*42  @4956
    float* bX  = csY + 1428;     // 34*36  @6384  rows r0-9..r0+24, cols c0-9..+24, 2 pad cols (0)
    float* bY  = bX + 1224;      // 34*36  @7608  (ends 8832)
    float* dX  = csX;            // 20*26  alias (cs dead)  rows r0-2..r0+17, cols c0-4..+19, 2 pad
    float* dD  = csX + 520;      // 20*26

    int tx = threadIdx.x, ty = threadIdx.y;
    int t = ty * 16 + tx;
    int c0 = blockIdx.x * 16, r0 = blockIdx.y * 16;

    if (t < 19)      { int d = t - 9;  sbx[t]      = __expf(-(float)(d * d) / 8145.0625f); }
    else if (t < 24) { int d = t - 21; sdy[t - 19] = __expf(-(float)(d * d) / 126.5625f); }

    // ---- prologue: wave-0 shuffle reduce of 256 min/max partials (no barriers) ----
    if (t < 64) {
        float2 p0 = partial[t], p1 = partial[t + 64], p2 = partial[t + 128], p3 = partial[t + 192];
        float mn = fminf(fminf(p0.x, p1.x), fminf(p2.x, p3.x));
        float mx = fmaxf(fmaxf(p0.y, p1.y), fmaxf(p2.y, p3.y));
        for (int off = 32; off > 0; off >>= 1) {
            mn = fminf(mn, __shfl_xor(mn, off));
            mx = fmaxf(mx, __shfl_xor(mx, off));
        }
        if (t == 0) {
            float sigma = r[0] * (mx - mn);
            float hh = 0.5f * sigma;
            sk2 = -1.4426950408889634f / (hh * hh);   // w_range = 2^(u^2*k2)
        }
    }

    // ---- stage X,y with halo (zero outside image) ----
    for (int i = t; i < 1764; i += 256) {
        int rr = i / 42, cc = i - rr * 42;
        int gr = r0 - 13 + rr, gc = c0 - 13 + cc;
        bool ok = ((unsigned)gr < 512u) & ((unsigned)gc < 512u);
        float xv = 0.f, yv = 0.f;
        if (ok) { xv = X[gr * W + gc]; yv = y[gr * W + gc]; }
        sX[i] = xv; sY[i] = yv;
    }
    __syncthreads();
    float k2 = sk2;
    v2f k2v = bc2(k2);

    // ---- 9-row column sums ----
    for (int i = t; i < 1428; i += 256) {
        int rr = i / 42, cc = i - rr * 42;
        float ax = 0.f, ay = 0.f;
#pragma unroll
        for (int k = 0; k < 9; ++k) { ax += sX[(rr + k) * 42 + cc]; ay += sY[(rr + k) * 42 + cc]; }
        csX[i] = ax; csY[i] = ay;
    }
    __syncthreads();

    // ---- 9-col sums -> SoA base tiles (pad cols 34,35 zeroed) ----
    const float inv81 = 1.0f / 81.0f;
    for (int i = t; i < 1224; i += 256) {
        int rr = i / 36, cc = i - rr * 36;
        float bx = 0.f, by = 0.f;
        if (cc < 34) {
            float ax = 0.f, ay = 0.f;
#pragma unroll
            for (int k = 0; k < 9; ++k) { ax += csX[rr * 42 + cc + k]; ay += csY[rr * 42 + cc + k]; }
            bx = ax * inv81; by = ay * inv81;
        }
        bX[i] = bx; bY[i] = by;
    }
    __syncthreads();

    // ---- SoA detail tiles (pad cols 24,25 zeroed); aliases dead cs region ----
    for (int i = t; i < 520; i += 256) {
        int rr = i / 26, cc = i - rr * 26;
        float xd = 0.f, dd = 0.f;
        if (cc < 24) {
            float Xb = bX[(rr + 7) * 36 + cc + 5];
            float yb = bY[(rr + 7) * 36 + cc + 5];
            float xc = sX[(rr + 11) * 42 + cc + 9];
            float yc = sY[(rr + 11) * 42 + cc + 9];
            xd = xc - Xb;
            dd = (yc - yb) - xd;
        }
        dX[i] = xd; dD[i] = dd;
    }
    __syncthreads();

    // ---- bilateral passes (all LDS reads), 1 px/thread, j-pairs packed ----
    int c = c0 + tx;
    int h = r0 + ty;

    // chunk mapping: output col -> owning chunk after overlap-trim
    int chunk = (c == 0) ? 0 : (c - 1) / 62;
    if (chunk > 8) chunk = 8;
    int s = 62 * chunk;
    int e = (chunk == 8) ? 512 : (s + 64);

    // column exponents (log2-domain spatial) with chunk mask folded in, as j-pairs
    const float ksb = -1.4426950408889634f / 8145.0625f;
    const float ksd = -1.4426950408889634f / 126.5625f;
    v2f cp[10];
#pragma unroll
    for (int p = 0; p < 10; ++p) {
        int j0 = 2 * p, j1 = 2 * p + 1;
        int n0 = c - 9 + j0, d0 = j0 - 9;
        int n1 = c - 9 + j1, d1 = j1 - 9;
        cp[p].x = ((n0 >= s) & (n0 < e)) ? ksb * (float)(d0 * d0) : -1e30f;
        cp[p].y = ((j1 < 19) & (n1 >= s) & (n1 < e)) ? ksb * (float)(d1 * d1) : -1e30f;
    }
    v2f cdp[5];
#pragma unroll
    for (int p = 0; p < 5; ++p) {
        int j0 = 2 * p, j1 = 2 * p + 1;
        int n0 = c - 4 + j0, d0 = j0 - 4;
        int n1 = c - 4 + j1, d1 = j1 - 4;
        cdp[p].x = ((n0 >= s) & (n0 < e)) ? ksd * (float)(d0 * d0) : -1e30f;
        cdp[p].y = ((j1 < 9) & (n1 >= s) & (n1 < e)) ? ksd * (float)(d1 * d1) : -1e30f;
    }

    v2f Xc2 = bc2(bX[(ty + 9) * 36 + tx + 9]);
    v2f Xd2 = bc2(dX[(ty + 2) * 26 + tx + 4]);

    // ---- base pass: 19x19 bilateral guided-filter stats, j packed 2-wide ----
    v2f s_w = bc2(0.f), s_wx = bc2(0.f), s_wy = bc2(0.f), s_wxx = bc2(0.f), s_wxy = bc2(0.f);
#pragma unroll 1
    for (int k = 0; k < 19; ++k) {
        int nh = h - 9 + k;
        if ((unsigned)nh >= 512u) continue;
        const float* xr = bX + (ty + k) * 36 + tx;
        const float* yr = bY + (ty + k) * 36 + tx;
        v2f xa[10], ya[10];
#pragma unroll
        for (int p = 0; p < 10; ++p) {         // batched row load (ds_read2-fusible)
            xa[p].x = xr[2 * p]; xa[p].y = xr[2 * p + 1];
            ya[p].x = yr[2 * p]; ya[p].y = yr[2 * p + 1];
        }
        v2f rs = bc2(0.f), rsx = bc2(0.f), rsy = bc2(0.f), rsxx = bc2(0.f), rsxy = bc2(0.f);
#pragma unroll
        for (int p = 0; p < 10; ++p) {
            v2f xv = xa[p], yv = ya[p];
            v2f u = xv - Xc2;
            v2f a = vfma(u * k2v, u, cp[p]);
            v2f w; w.x = fexp2(a.x); w.y = fexp2(a.y);
            v2f tt = w * xv;
            rs = rs + w;
            rsx = rsx + tt;
            rsy  = vfma(w,  yv, rsy);
            rsxx = vfma(tt, xv, rsxx);
            rsxy = vfma(tt, yv, rsxy);
        }
        v2f eyv = bc2(sbx[k]);
        s_w   = vfma(eyv, rs,   s_w);
        s_wx  = vfma(eyv, rsx,  s_wx);
        s_wy  = vfma(eyv, rsy,  s_wy);
        s_wxx = vfma(eyv, rsxx, s_wxx);
        s_wxy = vfma(eyv, rsxy, s_wxy);
    }

    // ---- detail pass: 5(h)x9(w) bilateral on residuals, j packed 2-wide ----
    v2f s_wd = bc2(0.f), s_v = bc2(0.f);
#pragma unroll 1
    for (int k = 0; k < 5; ++k) {
        int nh = h - 2 + k;
        if ((unsigned)nh >= 512u) continue;
        const float* dr = dX + (ty + k) * 26 + tx;
        const float* er = dD + (ty + k) * 26 + tx;
        v2f xa[5], ea[5];
#pragma unroll
        for (int p = 0; p < 5; ++p) {
            xa[p].x = dr[2 * p]; xa[p].y = dr[2 * p + 1];
            ea[p].x = er[2 * p]; ea[p].y = er[2 * p + 1];
        }
        v2f rs = bc2(0.f), rv = bc2(0.f);
#pragma unroll
        for (int p = 0; p < 5; ++p) {
            v2f u = xa[p] - Xd2;
            v2f a = vfma(u * k2v, u, cdp[p]);
            v2f w; w.x = fexp2(a.x); w.y = fexp2(a.y);
            rs = rs + w;
            rv = vfma(w, ea[p], rv);
        }
        v2f eyv = bc2(sdy[k]);
        s_wd = vfma(eyv, rs, s_wd);
        s_v  = vfma(eyv, rv, s_v);
    }

    // ---- combine pair lanes & store ----
    float sw   = s_w.x + s_w.y;
    float swx  = s_wx.x + s_wx.y;
    float swy  = s_wy.x + s_wy.y;
    float swxx = s_wxx.x + s_wxx.y;
    float swxy = s_wxy.x + s_wxy.y;
    float swd  = s_wd.x + s_wd.y;
    float sv   = s_v.x + s_v.y;

    float inv  = 1.0f / sw;
    float mx   = swx * inv, my = swy * inv;
    float varx = fmaf(-mx, mx, swxx * inv);
    float cov  = fmaf(-mx, my, swxy * inv);
    float A    = cov / (varx + 1e-6f);
    float b    = my - A * mx;
    float bd   = sv / swd;
    out[h * W + c] = fmaf(A, Xc2.x, b) + Xd2.x + bd;
}

extern "C" void kernel_launch(void* const* d_in, const int* in_sizes, int n_in,
                              void* d_out, int out_size, void* d_ws, size_t ws_size,
                              hipStream_t stream) {
    const float* X = (const float*)d_in[0];
    const float* y = (const float*)d_in[1];
    const float* r = (const float*)d_in[2];
    float* out = (float*)d_out;
    float2* partial = (float2*)d_ws;               // 256 float2, fully written each call

    k_minmax<<<256, 256, 0, stream>>>(y, partial);
    k_fused<<<dim3(32, 32), dim3(16, 16), 0, stream>>>(X, y, partial, r, out);
}